// Round 2
// baseline (420.369 us; speedup 1.0000x reference)
//
#include <hip/hip_runtime.h>
#include <hip/hip_bf16.h>

#define N_POINTS 100000
#define K_VOL 27
#define PAIRS 60000
#define CCH 64                     // C_IN == C_OUT == 64
#define DTILES (PAIRS / 32)        // 1875 double-tiles of 32 pairs (exact)
#define BX 76                      // grid (BX, 27) = 2052 blocks ~= 2 residency rounds
#define NWAVES 4                   // 256 threads

typedef __bf16 bf16x8 __attribute__((ext_vector_type(8)));
typedef float f32x4 __attribute__((ext_vector_type(4)));

// out[i][c] = bias[c]  (d_out is re-poisoned before every timed call)
__global__ __launch_bounds__(256) void init_out_kernel(
    const float* __restrict__ bias, float* __restrict__ out) {
  int tid = blockIdx.x * blockDim.x + threadIdx.x;  // over N_POINTS*16 float4s
  float4 b = ((const float4*)bias)[tid & 15];
  ((float4*)out)[tid] = b;
}

__device__ __forceinline__ bf16x8 cvt8(float4 a, float4 b) {
  bf16x8 f;
  f[0] = (__bf16)a.x; f[1] = (__bf16)a.y; f[2] = (__bf16)a.z; f[3] = (__bf16)a.w;
  f[4] = (__bf16)b.x; f[5] = (__bf16)b.y; f[6] = (__bf16)b.z; f[7] = (__bf16)b.w;
  return f;
}

__global__ __launch_bounds__(256, 4) void spconv_kernel(
    const float* __restrict__ input,   // [N, 64]
    const float* __restrict__ weight,  // [27, 64, 64]  (ci, co)
    const int* __restrict__ in_map,    // [27, PAIRS]
    const int* __restrict__ out_map,   // [27, PAIRS]
    float* __restrict__ out)           // [N, 64]
{
  const int k    = blockIdx.y;
  const int lane = threadIdx.x & 63;
  const int wave = threadIdx.x >> 6;
  const int col  = lane & 15;
  const int quad = lane >> 4;

  // ---- B fragments for this kernel offset: registers, reused across all tiles.
  // B[k=ci][n=co]: n = lane&15 (+16*nt), k = quad*8 + j (+32*s)
  const float* Wk = weight + k * (CCH * CCH);
  bf16x8 bfrag[4][2];
#pragma unroll
  for (int nt = 0; nt < 4; ++nt) {
    int co = nt * 16 + col;
#pragma unroll
    for (int s = 0; s < 2; ++s) {
      int ci0 = s * 32 + quad * 8;
      bf16x8 f;
#pragma unroll
      for (int j = 0; j < 8; ++j)
        f[j] = (__bf16)Wk[(ci0 + j) * CCH + co];
      bfrag[nt][s] = f;
    }
  }

  const int* im = in_map + k * PAIRS;
  const int* om = out_map + k * PAIRS;

  for (int t = blockIdx.x * NWAVES + wave; t < DTILES; t += BX * NWAVES) {
    const int pb = t * 32;

    // ---- issue ALL independent loads up front (indices, then both gathers)
    int rinA = im[pb + col];
    int rinB = im[pb + 16 + col];
    int orA[4], orB[4];
#pragma unroll
    for (int r = 0; r < 4; ++r) {
      orA[r] = om[pb + quad * 4 + r];
      orB[r] = om[pb + 16 + quad * 4 + r];
    }

    const float* rowA = input + (long)rinA * CCH + quad * 8;
    const float* rowB = input + (long)rinB * CCH + quad * 8;
    float4 a0 = *(const float4*)(rowA);
    float4 a1 = *(const float4*)(rowA + 4);
    float4 a2 = *(const float4*)(rowA + 32);
    float4 a3 = *(const float4*)(rowA + 36);
    float4 b0 = *(const float4*)(rowB);
    float4 b1 = *(const float4*)(rowB + 4);
    float4 b2 = *(const float4*)(rowB + 32);
    float4 b3 = *(const float4*)(rowB + 36);

    // A[m=pair][k=ci]: m = lane&15, ci = s*32 + quad*8 + j
    bf16x8 afA0 = cvt8(a0, a1), afA1 = cvt8(a2, a3);
    bf16x8 afB0 = cvt8(b0, b1), afB1 = cvt8(b2, b3);

    f32x4 accA[4], accB[4];
#pragma unroll
    for (int nt = 0; nt < 4; ++nt) {
      accA[nt] = (f32x4){0.f, 0.f, 0.f, 0.f};
      accB[nt] = (f32x4){0.f, 0.f, 0.f, 0.f};
      accA[nt] = __builtin_amdgcn_mfma_f32_16x16x32_bf16(afA0, bfrag[nt][0],
                                                         accA[nt], 0, 0, 0);
      accA[nt] = __builtin_amdgcn_mfma_f32_16x16x32_bf16(afA1, bfrag[nt][1],
                                                         accA[nt], 0, 0, 0);
      accB[nt] = __builtin_amdgcn_mfma_f32_16x16x32_bf16(afB0, bfrag[nt][0],
                                                         accB[nt], 0, 0, 0);
      accB[nt] = __builtin_amdgcn_mfma_f32_16x16x32_bf16(afB1, bfrag[nt][1],
                                                         accB[nt], 0, 0, 0);
    }

    // ---- scatter-add: C/D row = quad*4 + reg (pair), col = nt*16 + (lane&15)
#pragma unroll
    for (int r = 0; r < 4; ++r) {
      float* opA = out + (long)orA[r] * CCH + col;
      float* opB = out + (long)orB[r] * CCH + col;
#pragma unroll
      for (int nt = 0; nt < 4; ++nt) {
        atomicAdd(opA + nt * 16, accA[nt][r]);
        atomicAdd(opB + nt * 16, accB[nt][r]);
      }
    }
  }
}

extern "C" void kernel_launch(void* const* d_in, const int* in_sizes, int n_in,
                              void* d_out, int out_size, void* d_ws,
                              size_t ws_size, hipStream_t stream) {
  const float* input   = (const float*)d_in[0];
  const float* weight  = (const float*)d_in[1];
  const float* bias    = (const float*)d_in[2];
  const int*   in_map  = (const int*)d_in[3];
  const int*   out_map = (const int*)d_in[4];
  float* out = (float*)d_out;

  init_out_kernel<<<(N_POINTS * 16) / 256, 256, 0, stream>>>(bias, out);

  dim3 grid(BX, K_VOL);
  spconv_kernel<<<grid, 256, 0, stream>>>(input, weight, in_map, out_map, out);
}